// Round 4
// baseline (462.522 us; speedup 1.0000x reference)
//
#include <hip/hip_runtime.h>
#include <hip/hip_bf16.h>

// Problem constants
#define NROWS 16384      // B*C = 32*512
#define DDIM  256        // H*W
#define KEMB  8192
#define DECAYF 0.99f
#define ONE_MINUS_DECAY 0.01f
#define EPSF 1e-5f

// Output layout (all float32, concatenated in return order)
#define O_QST   0
#define O_LOSS  4194304
#define O_IDX   4194305
#define O_EMB   4210689
#define O_ECS   6307841
#define O_EES   6316033

typedef __attribute__((ext_vector_type(8))) short short8;
typedef __attribute__((ext_vector_type(4))) float f32x4;

// fp32 -> bf16 (RNE) as raw ushort, and back
static __device__ __forceinline__ unsigned short f2bf(float x) {
    unsigned int u = __float_as_uint(x);
    return (unsigned short)((u + 0x7fffu + ((u >> 16) & 1u)) >> 16);
}
static __device__ __forceinline__ float bf2f(unsigned short h) {
    return __uint_as_float(((unsigned int)h) << 16);
}

// async global->LDS, 16B per lane; lds base wave-uniform, lane i lands at +16*i
static __device__ __forceinline__ void gload16(const unsigned short* g, unsigned short* l) {
    __builtin_amdgcn_global_load_lds(
        (const __attribute__((address_space(1))) unsigned int*)g,
        (__attribute__((address_space(3))) unsigned int*)l, 16, 0, 0);
}

// ---------------- prep_e: one wave per code k ----------------
// e-norm (fp32 exact) + e hi/lo bf16 split (row-major) + ecs/ees decay init
// + block-partial 0.99*sum(ecs) atomic into scal[1] (scal pre-zeroed by memset)
__global__ __launch_bounds__(256) void prep_e(const float* __restrict__ emb,
                                              const float* __restrict__ ecs_in,
                                              const float* __restrict__ ees_in,
                                              float* __restrict__ enorm,
                                              unsigned short* __restrict__ eh,
                                              unsigned short* __restrict__ el,
                                              float* __restrict__ o_ecs,
                                              float* __restrict__ o_ees,
                                              float* __restrict__ scal) {
    const int w = threadIdx.x >> 6;
    const int k = blockIdx.x * 4 + w;
    const int lane = threadIdx.x & 63;
    const int base = k * DDIM + lane * 4;
    const float4 v = *(const float4*)&emb[base];
    ushort4 h, l;
    {
        const float* vp = (const float*)&v;
        unsigned short hh;
        hh = f2bf(vp[0]); h.x = hh; l.x = f2bf(vp[0] - bf2f(hh));
        hh = f2bf(vp[1]); h.y = hh; l.y = f2bf(vp[1] - bf2f(hh));
        hh = f2bf(vp[2]); h.z = hh; l.z = f2bf(vp[2] - bf2f(hh));
        hh = f2bf(vp[3]); h.w = hh; l.w = f2bf(vp[3] - bf2f(hh));
    }
    *(ushort4*)&eh[base] = h;
    *(ushort4*)&el[base] = l;
    const float4 s = *(const float4*)&ees_in[base];
    float4 so;
    so.x = DECAYF * s.x; so.y = DECAYF * s.y; so.z = DECAYF * s.z; so.w = DECAYF * s.w;
    *(float4*)&o_ees[base] = so;
    float sum = v.x * v.x + v.y * v.y + v.z * v.z + v.w * v.w;
    for (int o = 32; o; o >>= 1) sum += __shfl_down(sum, o);
    __shared__ float sc[4];
    if (lane == 0) {
        enorm[k] = sum;
        const float c = DECAYF * ecs_in[k];
        o_ecs[k] = c;
        sc[w] = c;
    }
    __syncthreads();
    if (threadIdx.x == 0) atomicAdd(&scal[1], sc[0] + sc[1] + sc[2] + sc[3]);
}

// ---------------- prep_z: one wave per row ----------------
__global__ __launch_bounds__(256) void prep_z(const float* __restrict__ z,
                                              unsigned short* __restrict__ zh,
                                              unsigned short* __restrict__ zl,
                                              unsigned long long* __restrict__ key64) {
    const int n = blockIdx.x * 4 + (threadIdx.x >> 6);
    const int lane = threadIdx.x & 63;
    const int base = n * DDIM + lane * 4;
    const float4 v = *(const float4*)&z[base];
    ushort4 h, l;
    {
        const float* vp = (const float*)&v;
        unsigned short hh;
        hh = f2bf(vp[0]); h.x = hh; l.x = f2bf(vp[0] - bf2f(hh));
        hh = f2bf(vp[1]); h.y = hh; l.y = f2bf(vp[1] - bf2f(hh));
        hh = f2bf(vp[2]); h.z = hh; l.z = f2bf(vp[2] - bf2f(hh));
        hh = f2bf(vp[3]); h.w = hh; l.w = f2bf(vp[3] - bf2f(hh));
    }
    *(ushort4*)&zh[base] = h;
    *(ushort4*)&zl[base] = l;
    if (lane == 0) key64[n] = ~0ull;
}

// ---------------- argmin_mfma: bf16x3 MFMA GEMM + fused argmin (R3-exact) ---
// Block 128x128, 4 waves (2x2 of 64x64), BK=32, pre-split bf16 inputs,
// global_load_lds width=16 staging for both operands.
// R1 (verified R2): chunk XOR-swizzle on both staging source and fragment
// reads -> BANK_CONFLICT 1.68e7 -> 0, 304 -> 279us.
// R4: 2-D supertiled XCD swizzle (T1). Dispatch id g -> XCD g%8 owns a fixed
// 16(row)x4(col) block supertile: per-XCD L2 working set 2.5MB < 4MB, A-panels
// pinned across rounds, B streams. Target: FETCH_SIZE 95MB -> ~30MB.
__global__ __launch_bounds__(256) void argmin_mfma(const unsigned short* __restrict__ zh,
                                                   const unsigned short* __restrict__ zl,
                                                   const unsigned short* __restrict__ eh,
                                                   const unsigned short* __restrict__ el,
                                                   const float* __restrict__ enorm,
                                                   unsigned long long* __restrict__ key64) {
    __shared__ unsigned short Ah[128][32];
    __shared__ unsigned short Al[128][32];
    __shared__ unsigned short Bh[128][32];
    __shared__ unsigned short Bl[128][32];

    const int tid = threadIdx.x;
    const int lane = tid & 63;
    const int wid = tid >> 6;
    const int wm = wid >> 1, wn = wid & 1;
    const int tx = lane & 15, quad = lane >> 4;

    // --- R4 XCD-supertile decode: bijective on 8192 = 8 XCD x 16 rounds x 64
    const unsigned int g = blockIdx.x;
    const unsigned int xcd = g & 7u;          // dispatch round-robin target
    const unsigned int j = g >> 3;            // per-XCD slot
    const unsigned int rnd = j >> 6;          // 16 rounds
    const unsigned int p = j & 63u;           // position in 16x4 supertile
    const int row0 = (int)(xcd * 16u + (p & 15u)) * 128;
    const int col0 = (int)(rnd * 4u + (p >> 4)) * 128;

    // staging: wave w covers rows [w*32, w*32+32); lane l -> row l>>2.
    // swizzled global chunk: g = (l&3) ^ ((l>>3)&3)
    const int w32 = wid * 32;
    const int r16 = lane >> 2;
    const int gc8 = (((lane & 3) ^ ((lane >> 3) & 3)) * 8);

    // fragment-read swizzle: chunk = quad ^ ((row>>1)&3); row low4 = tx
    const int sw = (quad ^ ((tx >> 1) & 3)) * 8;

    f32x4 acc[4][4];
#pragma unroll
    for (int i = 0; i < 4; i++)
#pragma unroll
        for (int j2 = 0; j2 < 4; j2++) acc[i][j2] = (f32x4){0.f, 0.f, 0.f, 0.f};

    for (int dstep = 0; dstep < DDIM; dstep += 32) {
        __syncthreads();   // all waves done reading previous tiles
#pragma unroll
        for (int i = 0; i < 2; i++) {
            const int lr = w32 + i * 16;
            const size_t ga = (size_t)(row0 + lr + r16) * DDIM + dstep + gc8;
            const size_t gb = (size_t)(col0 + lr + r16) * DDIM + dstep + gc8;
            gload16(&zh[ga], &Ah[lr][0]);
            gload16(&zl[ga], &Al[lr][0]);
            gload16(&eh[gb], &Bh[lr][0]);
            gload16(&el[gb], &Bl[lr][0]);
        }
        __syncthreads();   // drains vmcnt: tiles resident

        short8 aH[4], aL[4], bH[4], bL[4];
        const int ar = wm * 64 + tx;
        const int br = wn * 64 + tx;
#pragma unroll
        for (int mi = 0; mi < 4; mi++) {
            aH[mi] = *(const short8*)&Ah[ar + mi * 16][sw];
            aL[mi] = *(const short8*)&Al[ar + mi * 16][sw];
        }
#pragma unroll
        for (int nj = 0; nj < 4; nj++) {
            bH[nj] = *(const short8*)&Bh[br + nj * 16][sw];
            bL[nj] = *(const short8*)&Bl[br + nj * 16][sw];
        }
#pragma unroll
        for (int mi = 0; mi < 4; mi++)
#pragma unroll
            for (int nj = 0; nj < 4; nj++) {
                acc[mi][nj] = __builtin_amdgcn_mfma_f32_16x16x32_bf16(aH[mi], bH[nj], acc[mi][nj], 0, 0, 0);
                acc[mi][nj] = __builtin_amdgcn_mfma_f32_16x16x32_bf16(aL[mi], bH[nj], acc[mi][nj], 0, 0, 0);
                acc[mi][nj] = __builtin_amdgcn_mfma_f32_16x16x32_bf16(aH[mi], bL[nj], acc[mi][nj], 0, 0, 0);
            }
    }

    // epilogue: dist = ||e||^2 - 2 x.e ; fused argmin, k-ascending tie-break.
    // C/D layout: col = lane&15 (+nj*16), row = quad*4 + reg (+mi*16)
    float en[4];
    int colv[4];
#pragma unroll
    for (int nj = 0; nj < 4; nj++) {
        colv[nj] = col0 + wn * 64 + nj * 16 + tx;
        en[nj] = enorm[colv[nj]];
    }
#pragma unroll
    for (int mi = 0; mi < 4; mi++) {
#pragma unroll
        for (int r = 0; r < 4; r++) {
            unsigned long long best = ~0ull;
#pragma unroll
            for (int nj = 0; nj < 4; nj++) {
                float d = en[nj] - 2.0f * acc[mi][nj][r];
                unsigned int db = __float_as_uint(d);
                db = (db & 0x80000000u) ? ~db : (db | 0x80000000u);
                unsigned long long key = ((unsigned long long)db << 32) | (unsigned int)colv[nj];
                if (key < best) best = key;
            }
#pragma unroll
            for (int m = 1; m < 16; m <<= 1) {
                unsigned long long o = __shfl_xor(best, m);
                if (o < best) best = o;
            }
            if (tx == 0)
                atomicMin(&key64[row0 + wm * 64 + mi * 16 + quad * 4 + r], best);
        }
    }
}

// ---------------- quant_stats: 4 rows per wave, block-reduced loss ----------
// (R0-proven atomic tail: measured 153-171us total tail across sessions;
// R1's inverted-index variant measured 189 -> atomics are NOT the tail cost.)
__global__ __launch_bounds__(256) void quant_stats(const float* __restrict__ z,
                                                   const float* __restrict__ emb,
                                                   const unsigned long long* __restrict__ key64,
                                                   float* __restrict__ o_qst,
                                                   float* __restrict__ o_idx,
                                                   float* __restrict__ o_ecs,
                                                   float* __restrict__ o_ees,
                                                   float* __restrict__ scal) {
    const int w = threadIdx.x >> 6;
    const int lane = threadIdx.x & 63;
    const int nbase = blockIdx.x * 16 + w * 4;
    const int d0 = lane * 4;
    float ploc = 0.f;
#pragma unroll
    for (int r = 0; r < 4; r++) {
        const int n = nbase + r;
        const int k = (int)(key64[n] & 0xFFFFFFFFull);
        const float4 zv = *(const float4*)&z[n * DDIM + d0];
        const float4 ev = *(const float4*)&emb[k * DDIM + d0];
        const float dx = ev.x - zv.x, dy = ev.y - zv.y, dz2 = ev.z - zv.z, dw = ev.w - zv.w;
        float4 q;
        q.x = zv.x + dx; q.y = zv.y + dy; q.z = zv.z + dz2; q.w = zv.w + dw;
        *(float4*)&o_qst[n * DDIM + d0] = q;
        ploc += dx * dx + dy * dy + dz2 * dz2 + dw * dw;
        if (lane == 0) {
            o_idx[n] = (float)k;
            atomicAdd(&o_ecs[k], ONE_MINUS_DECAY);
        }
        atomicAdd(&o_ees[k * DDIM + d0 + 0], ONE_MINUS_DECAY * zv.x);
        atomicAdd(&o_ees[k * DDIM + d0 + 1], ONE_MINUS_DECAY * zv.y);
        atomicAdd(&o_ees[k * DDIM + d0 + 2], ONE_MINUS_DECAY * zv.z);
        atomicAdd(&o_ees[k * DDIM + d0 + 3], ONE_MINUS_DECAY * zv.w);
    }
    for (int o = 32; o; o >>= 1) ploc += __shfl_down(ploc, o);
    __shared__ float sh[4];
    if (lane == 0) sh[w] = ploc;
    __syncthreads();
    if (threadIdx.x == 0) atomicAdd(&scal[0], sh[0] + sh[1] + sh[2] + sh[3]);
}

// ---------------- finalize: new_embedding + loss scalar ----------------
// n_tot = 0.99*sum(ecs_in) + 0.01*NROWS   (scal[1] holds first term)
__global__ __launch_bounds__(256) void finalize_kernel(const float* __restrict__ o_ecs,
                                                       const float* __restrict__ o_ees,
                                                       const float* __restrict__ scal,
                                                       float* __restrict__ o_emb,
                                                       float* __restrict__ o_loss) {
    const int k = blockIdx.x;
    const int d = threadIdx.x;
    const float ntot = scal[1] + ONE_MINUS_DECAY * (float)NROWS;
    const float ecs = o_ecs[k];
    const float sm = (ecs + EPSF) / (ntot + (float)KEMB * EPSF) * ntot;
    o_emb[k * DDIM + d] = o_ees[k * DDIM + d] / sm;
    if (k == 0 && d == 0) o_loss[0] = 0.25f * scal[0] / (float)(NROWS * DDIM);
}

extern "C" void kernel_launch(void* const* d_in, const int* in_sizes, int n_in,
                              void* d_out, int out_size, void* d_ws, size_t ws_size,
                              hipStream_t stream) {
    const float* z   = (const float*)d_in[0];
    const float* emb = (const float*)d_in[1];
    const float* ecs = (const float*)d_in[2];
    const float* ees = (const float*)d_in[3];

    float* out = (float*)d_out;
    char*  ws  = (char*)d_ws;

    // small scratch at head of ws: norms (32KB), key64 (128KB), scal (8B)
    float* enorm = (float*)ws;                                    // 8192 f
    unsigned long long* key64 = (unsigned long long*)(ws + 32768);// 16384 u64
    float* scal = (float*)(ws + 32768 + 131072);

    // bf16 hi/lo scratch: prefer d_ws if large enough, else alias output
    // regions overwritten later (zh/zl in O_QST, eh/el in O_EMB).
    const size_t big0 = 32768 + 131072 + 256;                     // 164 KB
    const size_t bigbytes = (size_t)(NROWS + KEMB) * DDIM * 2 * 2;// 24 MB
    unsigned short *zh, *zl, *ehp, *elp;
    if (ws_size >= big0 + bigbytes) {
        zh  = (unsigned short*)(ws + big0);
        zl  = zh + NROWS * DDIM;
        ehp = zl + NROWS * DDIM;
        elp = ehp + KEMB * DDIM;
    } else {
        zh  = (unsigned short*)(out + O_QST);
        zl  = zh + NROWS * DDIM;
        ehp = (unsigned short*)(out + O_EMB);
        elp = ehp + KEMB * DDIM;
    }

    hipMemsetAsync(scal, 0, 2 * sizeof(float), stream);
    prep_e<<<KEMB / 4, 256, 0, stream>>>(emb, ecs, ees, enorm, ehp, elp,
                                         out + O_ECS, out + O_EES, scal);
    prep_z<<<NROWS / 4, 256, 0, stream>>>(z, zh, zl, key64);
    argmin_mfma<<<8192, 256, 0, stream>>>(zh, zl, ehp, elp, enorm, key64);
    quant_stats<<<NROWS / 16, 256, 0, stream>>>(z, emb, key64, out + O_QST, out + O_IDX,
                                                out + O_ECS, out + O_EES, scal);
    finalize_kernel<<<KEMB, DDIM, 0, stream>>>(out + O_ECS, out + O_EES, scal,
                                               out + O_EMB, out + O_LOSS);
}

// Round 5
// 434.960 us; speedup vs baseline: 1.0634x; 1.0634x over previous
//
#include <hip/hip_runtime.h>
#include <hip/hip_bf16.h>

// Problem constants
#define NROWS 16384      // B*C = 32*512
#define DDIM  256        // H*W
#define KEMB  8192
#define DECAYF 0.99f
#define ONE_MINUS_DECAY 0.01f
#define EPSF 1e-5f

// Output layout (all float32, concatenated in return order)
#define O_QST   0
#define O_LOSS  4194304
#define O_IDX   4194305
#define O_EMB   4210689
#define O_ECS   6307841
#define O_EES   6316033

typedef __attribute__((ext_vector_type(8))) short short8;
typedef __attribute__((ext_vector_type(4))) float f32x4;

// fp32 -> bf16 (RNE) as raw ushort, and back
static __device__ __forceinline__ unsigned short f2bf(float x) {
    unsigned int u = __float_as_uint(x);
    return (unsigned short)((u + 0x7fffu + ((u >> 16) & 1u)) >> 16);
}
static __device__ __forceinline__ float bf2f(unsigned short h) {
    return __uint_as_float(((unsigned int)h) << 16);
}

// async global->LDS, 16B per lane; lds base wave-uniform, lane i lands at +16*i
static __device__ __forceinline__ void gload16(const unsigned short* g, unsigned short* l) {
    __builtin_amdgcn_global_load_lds(
        (const __attribute__((address_space(1))) unsigned int*)g,
        (__attribute__((address_space(3))) unsigned int*)l, 16, 0, 0);
}

// ---------------- prep_all: fused prep_e + prep_z (R5) ----------------
// blocks [0,2048): codes — e-norm + e hi/lo split + ecs/ees decay init +
//                  per-block 0.99*sum(ecs) partial -> part_e[b] (no atomics,
//                  no memset needed).
// blocks [2048,6144): rows — z hi/lo split + key64 init.
__global__ __launch_bounds__(256) void prep_all(const float* __restrict__ z,
                                                const float* __restrict__ emb,
                                                const float* __restrict__ ecs_in,
                                                const float* __restrict__ ees_in,
                                                float* __restrict__ enorm,
                                                unsigned short* __restrict__ eh,
                                                unsigned short* __restrict__ el,
                                                unsigned short* __restrict__ zh,
                                                unsigned short* __restrict__ zl,
                                                float* __restrict__ o_ecs,
                                                float* __restrict__ o_ees,
                                                float* __restrict__ part_e,
                                                unsigned long long* __restrict__ key64) {
    const int b = blockIdx.x;
    const int w = threadIdx.x >> 6;
    const int lane = threadIdx.x & 63;
    if (b < 2048) {
        const int k = b * 4 + w;
        const int base = k * DDIM + lane * 4;
        const float4 v = *(const float4*)&emb[base];
        ushort4 h, l;
        {
            const float* vp = (const float*)&v;
            unsigned short hh;
            hh = f2bf(vp[0]); h.x = hh; l.x = f2bf(vp[0] - bf2f(hh));
            hh = f2bf(vp[1]); h.y = hh; l.y = f2bf(vp[1] - bf2f(hh));
            hh = f2bf(vp[2]); h.z = hh; l.z = f2bf(vp[2] - bf2f(hh));
            hh = f2bf(vp[3]); h.w = hh; l.w = f2bf(vp[3] - bf2f(hh));
        }
        *(ushort4*)&eh[base] = h;
        *(ushort4*)&el[base] = l;
        const float4 s = *(const float4*)&ees_in[base];
        float4 so;
        so.x = DECAYF * s.x; so.y = DECAYF * s.y; so.z = DECAYF * s.z; so.w = DECAYF * s.w;
        *(float4*)&o_ees[base] = so;
        float sum = v.x * v.x + v.y * v.y + v.z * v.z + v.w * v.w;
        for (int o = 32; o; o >>= 1) sum += __shfl_down(sum, o);
        __shared__ float sc[4];
        if (lane == 0) {
            enorm[k] = sum;
            const float c = DECAYF * ecs_in[k];
            o_ecs[k] = c;
            sc[w] = c;
        }
        __syncthreads();
        if (threadIdx.x == 0) part_e[b] = sc[0] + sc[1] + sc[2] + sc[3];
    } else {
        const int n = (b - 2048) * 4 + w;
        const int base = n * DDIM + lane * 4;
        const float4 v = *(const float4*)&z[base];
        ushort4 h, l;
        {
            const float* vp = (const float*)&v;
            unsigned short hh;
            hh = f2bf(vp[0]); h.x = hh; l.x = f2bf(vp[0] - bf2f(hh));
            hh = f2bf(vp[1]); h.y = hh; l.y = f2bf(vp[1] - bf2f(hh));
            hh = f2bf(vp[2]); h.z = hh; l.z = f2bf(vp[2] - bf2f(hh));
            hh = f2bf(vp[3]); h.w = hh; l.w = f2bf(vp[3] - bf2f(hh));
        }
        *(ushort4*)&zh[base] = h;
        *(ushort4*)&zl[base] = l;
        if (lane == 0) key64[n] = ~0ull;
    }
}

// ---------------- argmin_mfma: bf16x3 MFMA GEMM + fused argmin (R3-exact) ---
// Block 128x128, 4 waves (2x2 of 64x64), BK=32, pre-split bf16 inputs,
// global_load_lds width=16 staging for both operands.
// R1 (verified R2): chunk XOR-swizzle on both staging source and fragment
// reads -> BANK_CONFLICT 1.68e7 -> 0, 304 -> 279us.
// R4 tried XCD supertiling: FETCH 95->41MB but +2us (L3-fit, per m160) ->
// reverted in R5. Staging latency is NOT the limiter; structure ceiling is.
__global__ __launch_bounds__(256) void argmin_mfma(const unsigned short* __restrict__ zh,
                                                   const unsigned short* __restrict__ zl,
                                                   const unsigned short* __restrict__ eh,
                                                   const unsigned short* __restrict__ el,
                                                   const float* __restrict__ enorm,
                                                   unsigned long long* __restrict__ key64) {
    __shared__ unsigned short Ah[128][32];
    __shared__ unsigned short Al[128][32];
    __shared__ unsigned short Bh[128][32];
    __shared__ unsigned short Bl[128][32];

    const int tid = threadIdx.x;
    const int lane = tid & 63;
    const int wid = tid >> 6;
    const int wm = wid >> 1, wn = wid & 1;
    const int tx = lane & 15, quad = lane >> 4;

    const int row0 = blockIdx.x * 128;
    const int col0 = blockIdx.y * 128;

    // staging: wave w covers rows [w*32, w*32+32); lane l -> row l>>2.
    // swizzled global chunk: g = (l&3) ^ ((l>>3)&3)
    const int w32 = wid * 32;
    const int r16 = lane >> 2;
    const int gc8 = (((lane & 3) ^ ((lane >> 3) & 3)) * 8);

    // fragment-read swizzle: chunk = quad ^ ((row>>1)&3); row low4 = tx
    const int sw = (quad ^ ((tx >> 1) & 3)) * 8;

    f32x4 acc[4][4];
#pragma unroll
    for (int i = 0; i < 4; i++)
#pragma unroll
        for (int j = 0; j < 4; j++) acc[i][j] = (f32x4){0.f, 0.f, 0.f, 0.f};

    for (int dstep = 0; dstep < DDIM; dstep += 32) {
        __syncthreads();   // all waves done reading previous tiles
#pragma unroll
        for (int i = 0; i < 2; i++) {
            const int lr = w32 + i * 16;
            const size_t ga = (size_t)(row0 + lr + r16) * DDIM + dstep + gc8;
            const size_t gb = (size_t)(col0 + lr + r16) * DDIM + dstep + gc8;
            gload16(&zh[ga], &Ah[lr][0]);
            gload16(&zl[ga], &Al[lr][0]);
            gload16(&eh[gb], &Bh[lr][0]);
            gload16(&el[gb], &Bl[lr][0]);
        }
        __syncthreads();   // drains vmcnt: tiles resident

        short8 aH[4], aL[4], bH[4], bL[4];
        const int ar = wm * 64 + tx;
        const int br = wn * 64 + tx;
#pragma unroll
        for (int mi = 0; mi < 4; mi++) {
            aH[mi] = *(const short8*)&Ah[ar + mi * 16][sw];
            aL[mi] = *(const short8*)&Al[ar + mi * 16][sw];
        }
#pragma unroll
        for (int nj = 0; nj < 4; nj++) {
            bH[nj] = *(const short8*)&Bh[br + nj * 16][sw];
            bL[nj] = *(const short8*)&Bl[br + nj * 16][sw];
        }
#pragma unroll
        for (int mi = 0; mi < 4; mi++)
#pragma unroll
            for (int nj = 0; nj < 4; nj++) {
                acc[mi][nj] = __builtin_amdgcn_mfma_f32_16x16x32_bf16(aH[mi], bH[nj], acc[mi][nj], 0, 0, 0);
                acc[mi][nj] = __builtin_amdgcn_mfma_f32_16x16x32_bf16(aL[mi], bH[nj], acc[mi][nj], 0, 0, 0);
                acc[mi][nj] = __builtin_amdgcn_mfma_f32_16x16x32_bf16(aH[mi], bL[nj], acc[mi][nj], 0, 0, 0);
            }
    }

    // epilogue: dist = ||e||^2 - 2 x.e ; fused argmin, k-ascending tie-break.
    // C/D layout: col = lane&15 (+nj*16), row = quad*4 + reg (+mi*16)
    float en[4];
    int colv[4];
#pragma unroll
    for (int nj = 0; nj < 4; nj++) {
        colv[nj] = col0 + wn * 64 + nj * 16 + tx;
        en[nj] = enorm[colv[nj]];
    }
#pragma unroll
    for (int mi = 0; mi < 4; mi++) {
#pragma unroll
        for (int r = 0; r < 4; r++) {
            unsigned long long best = ~0ull;
#pragma unroll
            for (int nj = 0; nj < 4; nj++) {
                float d = en[nj] - 2.0f * acc[mi][nj][r];
                unsigned int db = __float_as_uint(d);
                db = (db & 0x80000000u) ? ~db : (db | 0x80000000u);
                unsigned long long key = ((unsigned long long)db << 32) | (unsigned int)colv[nj];
                if (key < best) best = key;
            }
#pragma unroll
            for (int m = 1; m < 16; m <<= 1) {
                unsigned long long o = __shfl_xor(best, m);
                if (o < best) best = o;
            }
            if (tx == 0)
                atomicMin(&key64[row0 + wm * 64 + mi * 16 + quad * 4 + r], best);
        }
    }
}

// ---------------- quant_stats: 4 rows per wave, per-block loss partial ------
// R5: loss partial -> part_q[blockIdx] (no scal atomic). The 16.8M ees
// atomicAdds stay UNCHANGED this round as the control for tail attribution.
__global__ __launch_bounds__(256) void quant_stats(const float* __restrict__ z,
                                                   const float* __restrict__ emb,
                                                   const unsigned long long* __restrict__ key64,
                                                   float* __restrict__ o_qst,
                                                   float* __restrict__ o_idx,
                                                   float* __restrict__ o_ecs,
                                                   float* __restrict__ o_ees,
                                                   float* __restrict__ part_q) {
    const int w = threadIdx.x >> 6;
    const int lane = threadIdx.x & 63;
    const int nbase = blockIdx.x * 16 + w * 4;
    const int d0 = lane * 4;
    float ploc = 0.f;
#pragma unroll
    for (int r = 0; r < 4; r++) {
        const int n = nbase + r;
        const int k = (int)(key64[n] & 0xFFFFFFFFull);
        const float4 zv = *(const float4*)&z[n * DDIM + d0];
        const float4 ev = *(const float4*)&emb[k * DDIM + d0];
        const float dx = ev.x - zv.x, dy = ev.y - zv.y, dz2 = ev.z - zv.z, dw = ev.w - zv.w;
        float4 q;
        q.x = zv.x + dx; q.y = zv.y + dy; q.z = zv.z + dz2; q.w = zv.w + dw;
        *(float4*)&o_qst[n * DDIM + d0] = q;
        ploc += dx * dx + dy * dy + dz2 * dz2 + dw * dw;
        if (lane == 0) {
            o_idx[n] = (float)k;
            atomicAdd(&o_ecs[k], ONE_MINUS_DECAY);
        }
        atomicAdd(&o_ees[k * DDIM + d0 + 0], ONE_MINUS_DECAY * zv.x);
        atomicAdd(&o_ees[k * DDIM + d0 + 1], ONE_MINUS_DECAY * zv.y);
        atomicAdd(&o_ees[k * DDIM + d0 + 2], ONE_MINUS_DECAY * zv.z);
        atomicAdd(&o_ees[k * DDIM + d0 + 3], ONE_MINUS_DECAY * zv.w);
    }
    for (int o = 32; o; o >>= 1) ploc += __shfl_down(ploc, o);
    __shared__ float sh[4];
    if (lane == 0) sh[w] = ploc;
    __syncthreads();
    if (threadIdx.x == 0) part_q[blockIdx.x] = sh[0] + sh[1] + sh[2] + sh[3];
}

// ---------------- finalize: new_embedding + loss scalar ----------------
// R5: ntot from a per-block redundant sum of part_e[2048] (8 loads/thread,
// L2-broadcast, ~2us aggregate) instead of a scalar atomic chain.
__global__ __launch_bounds__(256) void finalize_kernel(const float* __restrict__ o_ecs,
                                                       const float* __restrict__ o_ees,
                                                       const float* __restrict__ part_e,
                                                       const float* __restrict__ part_q,
                                                       float* __restrict__ o_emb,
                                                       float* __restrict__ o_loss) {
    const int k = blockIdx.x;
    const int d = threadIdx.x;
    __shared__ float red[256];
    float s = 0.f;
    for (int i = d; i < 2048; i += 256) s += part_e[i];
    red[d] = s;
    __syncthreads();
    for (int o = 128; o; o >>= 1) {
        if (d < o) red[d] += red[d + o];
        __syncthreads();
    }
    const float ntot = red[0] + ONE_MINUS_DECAY * (float)NROWS;
    const float ecs = o_ecs[k];
    const float sm = (ecs + EPSF) / (ntot + (float)KEMB * EPSF) * ntot;
    o_emb[k * DDIM + d] = o_ees[k * DDIM + d] / sm;
    if (k == 0) {
        __syncthreads();
        float s2 = 0.f;
        for (int i = d; i < 1024; i += 256) s2 += part_q[i];
        red[d] = s2;
        __syncthreads();
        for (int o = 128; o; o >>= 1) {
            if (d < o) red[d] += red[d + o];
            __syncthreads();
        }
        if (d == 0) o_loss[0] = 0.25f * red[0] / (float)(NROWS * DDIM);
    }
}

extern "C" void kernel_launch(void* const* d_in, const int* in_sizes, int n_in,
                              void* d_out, int out_size, void* d_ws, size_t ws_size,
                              hipStream_t stream) {
    const float* z   = (const float*)d_in[0];
    const float* emb = (const float*)d_in[1];
    const float* ecs = (const float*)d_in[2];
    const float* ees = (const float*)d_in[3];

    float* out = (float*)d_out;
    char*  ws  = (char*)d_ws;

    // ws head: enorm 32KB | key64 128KB | part_e 8KB | part_q 4KB
    float* enorm = (float*)ws;                                    // 8192 f
    unsigned long long* key64 = (unsigned long long*)(ws + 32768);// 16384 u64
    float* part_e = (float*)(ws + 163840);                        // 2048 f
    float* part_q = part_e + 2048;                                // 1024 f

    // bf16 hi/lo scratch: prefer d_ws if large enough, else alias output
    // regions overwritten later (zh/zl in O_QST, eh/el in O_EMB).
    const size_t big0 = 163840 + 8192 + 4096;                     // 176128
    const size_t bigbytes = (size_t)(NROWS + KEMB) * DDIM * 2 * 2;// 24 MB
    unsigned short *zh, *zl, *ehp, *elp;
    if (ws_size >= big0 + bigbytes) {
        zh  = (unsigned short*)(ws + big0);
        zl  = zh + NROWS * DDIM;
        ehp = zl + NROWS * DDIM;
        elp = ehp + KEMB * DDIM;
    } else {
        zh  = (unsigned short*)(out + O_QST);
        zl  = zh + NROWS * DDIM;
        ehp = (unsigned short*)(out + O_EMB);
        elp = ehp + KEMB * DDIM;
    }

    prep_all<<<6144, 256, 0, stream>>>(z, emb, ecs, ees, enorm, ehp, elp,
                                       zh, zl, out + O_ECS, out + O_EES,
                                       part_e, key64);
    argmin_mfma<<<dim3(NROWS / 128, KEMB / 128), 256, 0, stream>>>(zh, zl, ehp, elp, enorm, key64);
    quant_stats<<<NROWS / 16, 256, 0, stream>>>(z, emb, key64, out + O_QST, out + O_IDX,
                                                out + O_ECS, out + O_EES, part_q);
    finalize_kernel<<<KEMB, DDIM, 0, stream>>>(out + O_ECS, out + O_EES,
                                               part_e, part_q,
                                               out + O_EMB, out + O_LOSS);
}

// Round 6
// 389.725 us; speedup vs baseline: 1.1868x; 1.1161x over previous
//
#include <hip/hip_runtime.h>
#include <hip/hip_bf16.h>

// Problem constants
#define NROWS 16384      // B*C = 32*512
#define DDIM  256        // H*W
#define KEMB  8192
#define DECAYF 0.99f
#define ONE_MINUS_DECAY 0.01f
#define EPSF 1e-5f

// Output layout (all float32, concatenated in return order)
#define O_QST   0
#define O_LOSS  4194304
#define O_IDX   4194305
#define O_EMB   4210689
#define O_ECS   6307841
#define O_EES   6316033

typedef __attribute__((ext_vector_type(8))) short short8;
typedef __attribute__((ext_vector_type(4))) float f32x4;

// fp32 -> bf16 (RNE) as raw ushort, and back
static __device__ __forceinline__ unsigned short f2bf(float x) {
    unsigned int u = __float_as_uint(x);
    return (unsigned short)((u + 0x7fffu + ((u >> 16) & 1u)) >> 16);
}
static __device__ __forceinline__ float bf2f(unsigned short h) {
    return __uint_as_float(((unsigned int)h) << 16);
}

// async global->LDS, 16B per lane; lds base wave-uniform, lane i lands at +16*i
static __device__ __forceinline__ void gload16(const unsigned short* g, unsigned short* l) {
    __builtin_amdgcn_global_load_lds(
        (const __attribute__((address_space(1))) unsigned int*)g,
        (__attribute__((address_space(3))) unsigned int*)l, 16, 0, 0);
}

// ---------------- prep_all: fused prep_e + prep_z (R5, verified 435us) ------
__global__ __launch_bounds__(256) void prep_all(const float* __restrict__ z,
                                                const float* __restrict__ emb,
                                                const float* __restrict__ ecs_in,
                                                const float* __restrict__ ees_in,
                                                float* __restrict__ enorm,
                                                unsigned short* __restrict__ eh,
                                                unsigned short* __restrict__ el,
                                                unsigned short* __restrict__ zh,
                                                unsigned short* __restrict__ zl,
                                                float* __restrict__ o_ecs,
                                                float* __restrict__ o_ees,
                                                float* __restrict__ part_e,
                                                unsigned long long* __restrict__ key64) {
    const int b = blockIdx.x;
    const int w = threadIdx.x >> 6;
    const int lane = threadIdx.x & 63;
    if (b < 2048) {
        const int k = b * 4 + w;
        const int base = k * DDIM + lane * 4;
        const float4 v = *(const float4*)&emb[base];
        ushort4 h, l;
        {
            const float* vp = (const float*)&v;
            unsigned short hh;
            hh = f2bf(vp[0]); h.x = hh; l.x = f2bf(vp[0] - bf2f(hh));
            hh = f2bf(vp[1]); h.y = hh; l.y = f2bf(vp[1] - bf2f(hh));
            hh = f2bf(vp[2]); h.z = hh; l.z = f2bf(vp[2] - bf2f(hh));
            hh = f2bf(vp[3]); h.w = hh; l.w = f2bf(vp[3] - bf2f(hh));
        }
        *(ushort4*)&eh[base] = h;
        *(ushort4*)&el[base] = l;
        const float4 s = *(const float4*)&ees_in[base];
        float4 so;
        so.x = DECAYF * s.x; so.y = DECAYF * s.y; so.z = DECAYF * s.z; so.w = DECAYF * s.w;
        *(float4*)&o_ees[base] = so;
        float sum = v.x * v.x + v.y * v.y + v.z * v.z + v.w * v.w;
        for (int o = 32; o; o >>= 1) sum += __shfl_down(sum, o);
        __shared__ float sc[4];
        if (lane == 0) {
            enorm[k] = sum;
            const float c = DECAYF * ecs_in[k];
            o_ecs[k] = c;
            sc[w] = c;
        }
        __syncthreads();
        if (threadIdx.x == 0) part_e[b] = sc[0] + sc[1] + sc[2] + sc[3];
    } else {
        const int n = (b - 2048) * 4 + w;
        const int base = n * DDIM + lane * 4;
        const float4 v = *(const float4*)&z[base];
        ushort4 h, l;
        {
            const float* vp = (const float*)&v;
            unsigned short hh;
            hh = f2bf(vp[0]); h.x = hh; l.x = f2bf(vp[0] - bf2f(hh));
            hh = f2bf(vp[1]); h.y = hh; l.y = f2bf(vp[1] - bf2f(hh));
            hh = f2bf(vp[2]); h.z = hh; l.z = f2bf(vp[2] - bf2f(hh));
            hh = f2bf(vp[3]); h.w = hh; l.w = f2bf(vp[3] - bf2f(hh));
        }
        *(ushort4*)&zh[base] = h;
        *(ushort4*)&zl[base] = l;
        if (lane == 0) key64[n] = ~0ull;
    }
}

// ---------------- argmin_mfma (R6): 256x256 tile, 8 waves, dbuf LDS --------
// bf16x3 MFMA GEMM + fused argmin, numerically identical to the 128x128
// version (same per-fragment MFMA chain order).
// - 2x staging intensity vs 128^2 (64KB staged per 65536 outputs)
// - double-buffered: STAGE(next) issued BEFORE compute(cur); the single
//   end-of-step __syncthreads (implicit vmcnt drain) lands after ~930cyc
//   of MFMA, so DMA latency is hidden within the block.
// - proven R2 chunk-XOR swizzle pair kept verbatim (slab-of-16 relative).
__global__ __launch_bounds__(512) void argmin_mfma(const unsigned short* __restrict__ zh,
                                                   const unsigned short* __restrict__ zl,
                                                   const unsigned short* __restrict__ eh,
                                                   const unsigned short* __restrict__ el,
                                                   const float* __restrict__ enorm,
                                                   unsigned long long* __restrict__ key64) {
    __shared__ unsigned short Ah[2][256][32];
    __shared__ unsigned short Al[2][256][32];
    __shared__ unsigned short Bh[2][256][32];
    __shared__ unsigned short Bl[2][256][32];

    const int tid = threadIdx.x;
    const int lane = tid & 63;
    const int wid = tid >> 6;          // 0..7
    const int wm = wid >> 2;           // 0..1: row half (128 rows)
    const int wn = wid & 3;            // 0..3: col quarter (64 cols)
    const int tx = lane & 15, quad = lane >> 4;

    const int row0 = blockIdx.x * 256;
    const int col0 = blockIdx.y * 256;

    // staging: lane l -> row l>>2 within a 16-row slab, swizzled 16B chunk
    const int r16 = lane >> 2;
    const int gc8 = (((lane & 3) ^ ((lane >> 3) & 3)) * 8);
    // fragment-read swizzle: chunk = quad ^ ((row>>1)&3); row low4 = tx
    const int sw = (quad ^ ((tx >> 1) & 3)) * 8;

    // wave-uniform staging role: waves {0,1}->Ah {2,3}->Al {4,5}->Bh {6,7}->Bl
    // even wave of each pair: slabs 0-7, odd: slabs 8-15 (16 rows each)
    const unsigned short* gsrc = (wid < 2) ? zh : (wid < 4) ? zl : (wid < 6) ? eh : el;
    unsigned short* lds0 = (wid < 2) ? &Ah[0][0][0] : (wid < 4) ? &Al[0][0][0]
                         : (wid < 6) ? &Bh[0][0][0] : &Bl[0][0][0];
    const int gbase0 = (wid < 4) ? row0 : col0;
    const int slab0 = (wid & 1) * 8;

    auto stage = [&](int b, int dk) {
#pragma unroll
        for (int i = 0; i < 8; i++) {
            const int lr = (slab0 + i) * 16;
            gload16(&gsrc[(size_t)(gbase0 + lr + r16) * DDIM + dk + gc8],
                    lds0 + b * 8192 + lr * 32);
        }
    };

    f32x4 acc[8][4];
#pragma unroll
    for (int i = 0; i < 8; i++)
#pragma unroll
        for (int j = 0; j < 4; j++) acc[i][j] = (f32x4){0.f, 0.f, 0.f, 0.f};

    stage(0, 0);
    __syncthreads();   // buf0 resident

    for (int d8 = 0; d8 < 8; d8++) {
        const int cur = d8 & 1;
        if (d8 < 7) stage(cur ^ 1, (d8 + 1) * 32);   // in flight during MFMA

        short8 bH[4], bL[4];
        const int bbase = wn * 64 + tx;
#pragma unroll
        for (int nj = 0; nj < 4; nj++) {
            bH[nj] = *(const short8*)&Bh[cur][bbase + nj * 16][sw];
            bL[nj] = *(const short8*)&Bl[cur][bbase + nj * 16][sw];
        }
        const int abase = wm * 128 + tx;
#pragma unroll
        for (int mi = 0; mi < 8; mi++) {
            const short8 aH = *(const short8*)&Ah[cur][abase + mi * 16][sw];
            const short8 aL = *(const short8*)&Al[cur][abase + mi * 16][sw];
#pragma unroll
            for (int nj = 0; nj < 4; nj++) {
                acc[mi][nj] = __builtin_amdgcn_mfma_f32_16x16x32_bf16(aH, bH[nj], acc[mi][nj], 0, 0, 0);
                acc[mi][nj] = __builtin_amdgcn_mfma_f32_16x16x32_bf16(aL, bH[nj], acc[mi][nj], 0, 0, 0);
                acc[mi][nj] = __builtin_amdgcn_mfma_f32_16x16x32_bf16(aH, bL[nj], acc[mi][nj], 0, 0, 0);
            }
        }
        __syncthreads();   // all reads of cur done + next buf resident
    }

    // epilogue: dist = ||e||^2 - 2 x.e ; fused argmin, k-ascending tie-break.
    // C/D layout: col = lane&15 (+nj*16), row = quad*4 + reg (+mi*16)
    float en[4];
    int colv[4];
#pragma unroll
    for (int nj = 0; nj < 4; nj++) {
        colv[nj] = col0 + wn * 64 + nj * 16 + tx;
        en[nj] = enorm[colv[nj]];
    }
#pragma unroll
    for (int mi = 0; mi < 8; mi++) {
#pragma unroll
        for (int r = 0; r < 4; r++) {
            unsigned long long best = ~0ull;
#pragma unroll
            for (int nj = 0; nj < 4; nj++) {
                float d = en[nj] - 2.0f * acc[mi][nj][r];
                unsigned int db = __float_as_uint(d);
                db = (db & 0x80000000u) ? ~db : (db | 0x80000000u);
                unsigned long long key = ((unsigned long long)db << 32) | (unsigned int)colv[nj];
                if (key < best) best = key;
            }
#pragma unroll
            for (int m = 1; m < 16; m <<= 1) {
                unsigned long long o = __shfl_xor(best, m);
                if (o < best) best = o;
            }
            if (tx == 0)
                atomicMin(&key64[row0 + wm * 128 + mi * 16 + quad * 4 + r], best);
        }
    }
}

// ---------------- quant_stats: 4 rows per wave, per-block loss partial ------
// (R5-verified; 16.8M ees atomics unchanged — tail control)
__global__ __launch_bounds__(256) void quant_stats(const float* __restrict__ z,
                                                   const float* __restrict__ emb,
                                                   const unsigned long long* __restrict__ key64,
                                                   float* __restrict__ o_qst,
                                                   float* __restrict__ o_idx,
                                                   float* __restrict__ o_ecs,
                                                   float* __restrict__ o_ees,
                                                   float* __restrict__ part_q) {
    const int w = threadIdx.x >> 6;
    const int lane = threadIdx.x & 63;
    const int nbase = blockIdx.x * 16 + w * 4;
    const int d0 = lane * 4;
    float ploc = 0.f;
#pragma unroll
    for (int r = 0; r < 4; r++) {
        const int n = nbase + r;
        const int k = (int)(key64[n] & 0xFFFFFFFFull);
        const float4 zv = *(const float4*)&z[n * DDIM + d0];
        const float4 ev = *(const float4*)&emb[k * DDIM + d0];
        const float dx = ev.x - zv.x, dy = ev.y - zv.y, dz2 = ev.z - zv.z, dw = ev.w - zv.w;
        float4 q;
        q.x = zv.x + dx; q.y = zv.y + dy; q.z = zv.z + dz2; q.w = zv.w + dw;
        *(float4*)&o_qst[n * DDIM + d0] = q;
        ploc += dx * dx + dy * dy + dz2 * dz2 + dw * dw;
        if (lane == 0) {
            o_idx[n] = (float)k;
            atomicAdd(&o_ecs[k], ONE_MINUS_DECAY);
        }
        atomicAdd(&o_ees[k * DDIM + d0 + 0], ONE_MINUS_DECAY * zv.x);
        atomicAdd(&o_ees[k * DDIM + d0 + 1], ONE_MINUS_DECAY * zv.y);
        atomicAdd(&o_ees[k * DDIM + d0 + 2], ONE_MINUS_DECAY * zv.z);
        atomicAdd(&o_ees[k * DDIM + d0 + 3], ONE_MINUS_DECAY * zv.w);
    }
    for (int o = 32; o; o >>= 1) ploc += __shfl_down(ploc, o);
    __shared__ float sh[4];
    if (lane == 0) sh[w] = ploc;
    __syncthreads();
    if (threadIdx.x == 0) part_q[blockIdx.x] = sh[0] + sh[1] + sh[2] + sh[3];
}

// ---------------- finalize: new_embedding + loss scalar (R5-verified) -------
__global__ __launch_bounds__(256) void finalize_kernel(const float* __restrict__ o_ecs,
                                                       const float* __restrict__ o_ees,
                                                       const float* __restrict__ part_e,
                                                       const float* __restrict__ part_q,
                                                       float* __restrict__ o_emb,
                                                       float* __restrict__ o_loss) {
    const int k = blockIdx.x;
    const int d = threadIdx.x;
    __shared__ float red[256];
    float s = 0.f;
    for (int i = d; i < 2048; i += 256) s += part_e[i];
    red[d] = s;
    __syncthreads();
    for (int o = 128; o; o >>= 1) {
        if (d < o) red[d] += red[d + o];
        __syncthreads();
    }
    const float ntot = red[0] + ONE_MINUS_DECAY * (float)NROWS;
    const float ecs = o_ecs[k];
    const float sm = (ecs + EPSF) / (ntot + (float)KEMB * EPSF) * ntot;
    o_emb[k * DDIM + d] = o_ees[k * DDIM + d] / sm;
    if (k == 0) {
        __syncthreads();
        float s2 = 0.f;
        for (int i = d; i < 1024; i += 256) s2 += part_q[i];
        red[d] = s2;
        __syncthreads();
        for (int o = 128; o; o >>= 1) {
            if (d < o) red[d] += red[d + o];
            __syncthreads();
        }
        if (d == 0) o_loss[0] = 0.25f * red[0] / (float)(NROWS * DDIM);
    }
}

extern "C" void kernel_launch(void* const* d_in, const int* in_sizes, int n_in,
                              void* d_out, int out_size, void* d_ws, size_t ws_size,
                              hipStream_t stream) {
    const float* z   = (const float*)d_in[0];
    const float* emb = (const float*)d_in[1];
    const float* ecs = (const float*)d_in[2];
    const float* ees = (const float*)d_in[3];

    float* out = (float*)d_out;
    char*  ws  = (char*)d_ws;

    // ws head: enorm 32KB | key64 128KB | part_e 8KB | part_q 4KB
    float* enorm = (float*)ws;                                    // 8192 f
    unsigned long long* key64 = (unsigned long long*)(ws + 32768);// 16384 u64
    float* part_e = (float*)(ws + 163840);                        // 2048 f
    float* part_q = part_e + 2048;                                // 1024 f

    // bf16 hi/lo scratch: prefer d_ws if large enough, else alias output
    // regions overwritten later (zh/zl in O_QST, eh/el in O_EMB).
    const size_t big0 = 163840 + 8192 + 4096;                     // 176128
    const size_t bigbytes = (size_t)(NROWS + KEMB) * DDIM * 2 * 2;// 24 MB
    unsigned short *zh, *zl, *ehp, *elp;
    if (ws_size >= big0 + bigbytes) {
        zh  = (unsigned short*)(ws + big0);
        zl  = zh + NROWS * DDIM;
        ehp = zl + NROWS * DDIM;
        elp = ehp + KEMB * DDIM;
    } else {
        zh  = (unsigned short*)(out + O_QST);
        zl  = zh + NROWS * DDIM;
        ehp = (unsigned short*)(out + O_EMB);
        elp = ehp + KEMB * DDIM;
    }

    prep_all<<<6144, 256, 0, stream>>>(z, emb, ecs, ees, enorm, ehp, elp,
                                       zh, zl, out + O_ECS, out + O_EES,
                                       part_e, key64);
    argmin_mfma<<<dim3(NROWS / 256, KEMB / 256), 512, 0, stream>>>(zh, zl, ehp, elp, enorm, key64);
    quant_stats<<<NROWS / 16, 256, 0, stream>>>(z, emb, key64, out + O_QST, out + O_IDX,
                                                out + O_ECS, out + O_EES, part_q);
    finalize_kernel<<<KEMB, DDIM, 0, stream>>>(out + O_ECS, out + O_EES,
                                               part_e, part_q,
                                               out + O_EMB, out + O_LOSS);
}